// Round 1
// baseline (365.080 us; speedup 1.0000x reference)
//
#include <hip/hip_runtime.h>
#include <math.h>

// PropagatorBlock: B=512, H=1024, K=256, V=512, MUL=4
// Fixed shapes -> hardcode.
constexpr int B_ = 512;
constexpr int H_ = 1024;
constexpr int K_ = 256;
constexpr int V_ = 512;
constexpr int F_ = 4096;  // MUL*H

typedef __attribute__((ext_vector_type(8))) short bf16x8;
typedef __attribute__((ext_vector_type(4))) float f32x4;

// ---- helpers ----------------------------------------------------------
static __device__ __forceinline__ unsigned short f2bf(float f) {
  union { float f; unsigned int u; } a; a.f = f;
  unsigned int u = a.u;
  return (unsigned short)((u + 0x7FFFu + ((u >> 16) & 1u)) >> 16);  // RNE
}

// block of 256 threads -> sum over all threads (uses 4-entry sbuf)
static __device__ __forceinline__ float block_sum256(float v, float* sbuf) {
#pragma unroll
  for (int o = 32; o > 0; o >>= 1) v += __shfl_down(v, o, 64);
  const int w = threadIdx.x >> 6;
  __syncthreads();  // protect sbuf against previous use
  if ((threadIdx.x & 63) == 0) sbuf[w] = v;
  __syncthreads();
  return sbuf[0] + sbuf[1] + sbuf[2] + sbuf[3];
}

// ---- weight transpose + f32->bf16:  W[R][C] -> WT[C][R] ---------------
__global__ __launch_bounds__(256) void transpose_bf16(
    const float* __restrict__ W, unsigned short* __restrict__ WT, int R, int C) {
  __shared__ float t[32][33];
  const int tx = threadIdx.x & 31, ty = threadIdx.x >> 5;
  const int c0 = blockIdx.x << 5, r0 = blockIdx.y << 5;
#pragma unroll
  for (int i = 0; i < 32; i += 8) t[ty + i][tx] = W[(size_t)(r0 + ty + i) * C + c0 + tx];
  __syncthreads();
#pragma unroll
  for (int i = 0; i < 32; i += 8)
    WT[(size_t)(c0 + ty + i) * R + r0 + tx] = f2bf(t[tx][ty + i]);
}

// ---- generic bf16 MFMA GEMM: C[M][N] = A[M][K] * BT[N][K]^T -----------
// 64x64 tile, BK=32, 4 waves each computing a 32x32 quadrant via 2x2
// 16x16x32 fragments. All shapes here divide 64/64/32 exactly.
__global__ __launch_bounds__(256) void gemm_bt(
    const unsigned short* __restrict__ A, const unsigned short* __restrict__ BT,
    float* __restrict__ C, int M, int N, int K) {
  __shared__ unsigned short lsa[64][40];  // +8 pad -> 80B row stride (bank-balanced)
  __shared__ unsigned short lsb[64][40];
  const int tid = threadIdx.x;
  const int m0 = blockIdx.y << 6, n0 = blockIdx.x << 6;
  const int wave = tid >> 6, lane = tid & 63;
  const int wm = (wave >> 1) << 5, wn = (wave & 1) << 5;
  const int l15 = lane & 15, lg = lane >> 4;
  const int srow = tid >> 2, skc = (tid & 3) << 3;

  f32x4 acc[2][2] = {};

  const unsigned short* aptr = A + (size_t)(m0 + srow) * K + skc;
  const unsigned short* bptr = BT + (size_t)(n0 + srow) * K + skc;

  for (int k0 = 0; k0 < K; k0 += 32) {
    *(uint4*)&lsa[srow][skc] = *(const uint4*)(aptr + k0);
    *(uint4*)&lsb[srow][skc] = *(const uint4*)(bptr + k0);
    __syncthreads();
    bf16x8 a0 = *(const bf16x8*)&lsa[wm + l15][lg << 3];
    bf16x8 a1 = *(const bf16x8*)&lsa[wm + 16 + l15][lg << 3];
    bf16x8 b0 = *(const bf16x8*)&lsb[wn + l15][lg << 3];
    bf16x8 b1 = *(const bf16x8*)&lsb[wn + 16 + l15][lg << 3];
    acc[0][0] = __builtin_amdgcn_mfma_f32_16x16x32_bf16(a0, b0, acc[0][0], 0, 0, 0);
    acc[0][1] = __builtin_amdgcn_mfma_f32_16x16x32_bf16(a0, b1, acc[0][1], 0, 0, 0);
    acc[1][0] = __builtin_amdgcn_mfma_f32_16x16x32_bf16(a1, b0, acc[1][0], 0, 0, 0);
    acc[1][1] = __builtin_amdgcn_mfma_f32_16x16x32_bf16(a1, b1, acc[1][1], 0, 0, 0);
    __syncthreads();
  }
#pragma unroll
  for (int fm = 0; fm < 2; ++fm)
#pragma unroll
    for (int fn = 0; fn < 2; ++fn) {
      const int r = m0 + wm + fm * 16 + (lg << 2);
      const int c = n0 + wn + fn * 16 + l15;
      float* cp = C + (size_t)r * N + c;
#pragma unroll
      for (int i = 0; i < 4; ++i) cp[(size_t)i * N] = acc[fm][fn][i];
    }
}

// ---- norm1: h1 = bf16(rmsnorm(x)*scale1) ------------------------------
__global__ __launch_bounds__(256) void norm1_kernel(
    const float* __restrict__ x, const float* __restrict__ scale,
    unsigned short* __restrict__ out) {
  __shared__ float sbuf[4];
  const int b = blockIdx.x, tid = threadIdx.x;
  const float* xr = x + ((size_t)b << 10);
  float loc[4]; float ss = 0.f;
#pragma unroll
  for (int it = 0; it < 4; ++it) { float v = xr[(it << 8) + tid]; loc[it] = v; ss += v * v; }
  ss = block_sum256(ss, sbuf);
  const float r = rsqrtf(ss * (1.f / 1024.f) + 1e-6f);
  unsigned short* orow = out + ((size_t)b << 10);
#pragma unroll
  for (int it = 0; it < 4; ++it) { const int j = (it << 8) + tid; orow[j] = f2bf(loc[it] * r * scale[j]); }
}

// ---- rmsnorm over K=256 rows, * mul -----------------------------------
__global__ __launch_bounds__(256) void rmsnorm256(
    const float* __restrict__ in, float* __restrict__ out, float mul) {
  __shared__ float sbuf[4];
  const int b = blockIdx.x, tid = threadIdx.x;
  const float v = in[((size_t)b << 8) + tid];
  const float ss = block_sum256(v * v, sbuf);
  const float r = rsqrtf(ss * (1.f / 256.f) + 1e-6f) * mul;
  out[((size_t)b << 8) + tid] = v * r;
}

// ---- einsum1: rv[b,v] = sum_k mem[b,k,v]*rk[b,k]  (bf16 out) ----------
__global__ __launch_bounds__(256) void read_einsum(
    const float* __restrict__ mem, const float* __restrict__ rk,
    unsigned short* __restrict__ rv) {
  __shared__ float lrk[256];
  __shared__ float part[8][32][4];
  const int tid = threadIdx.x;
  const int b = blockIdx.x >> 2;
  const int v0 = (blockIdx.x & 3) << 7;  // 128 v per block
  lrk[tid] = rk[((size_t)b << 8) + tid];
  __syncthreads();
  const int vq = tid & 31, kg = tid >> 5;
  const float* base = mem + (((size_t)b << 8) + (kg << 5)) * 512 + v0 + (vq << 2);
  float a0 = 0, a1 = 0, a2 = 0, a3 = 0;
#pragma unroll 8
  for (int kk = 0; kk < 32; ++kk) {
    const float4 m4 = *(const float4*)(base + (size_t)kk * 512);
    const float s = lrk[(kg << 5) + kk];
    a0 += s * m4.x; a1 += s * m4.y; a2 += s * m4.z; a3 += s * m4.w;
  }
  part[kg][vq][0] = a0; part[kg][vq][1] = a1; part[kg][vq][2] = a2; part[kg][vq][3] = a3;
  __syncthreads();
  if (kg == 0) {
    float s0 = 0, s1 = 0, s2 = 0, s3 = 0;
#pragma unroll
    for (int g = 0; g < 8; ++g) {
      s0 += part[g][vq][0]; s1 += part[g][vq][1]; s2 += part[g][vq][2]; s3 += part[g][vq][3];
    }
    const size_t o = ((size_t)b << 9) + v0 + (vq << 2);
    rv[o] = f2bf(s0); rv[o + 1] = f2bf(s1); rv[o + 2] = f2bf(s2); rv[o + 3] = f2bf(s3);
  }
}

// ---- x1 = x + gamma1*proj; h2 = bf16(rmsnorm(x1)*scale2) --------------
__global__ __launch_bounds__(256) void add1_norm2(
    const float* __restrict__ x, const float* __restrict__ proj,
    const float* __restrict__ gamma1, const float* __restrict__ scale2,
    float* __restrict__ x1, unsigned short* __restrict__ h2) {
  __shared__ float sbuf[4];
  const int b = blockIdx.x, tid = threadIdx.x;
  const size_t ro = (size_t)b << 10;
  float loc[4]; float ss = 0.f;
#pragma unroll
  for (int it = 0; it < 4; ++it) {
    const int j = (it << 8) + tid;
    const float v = x[ro + j] + gamma1[j] * proj[ro + j];
    x1[ro + j] = v; loc[it] = v; ss += v * v;
  }
  ss = block_sum256(ss, sbuf);
  const float r = rsqrtf(ss * (1.f / 1024.f) + 1e-6f);
#pragma unroll
  for (int it = 0; it < 4; ++it) { const int j = (it << 8) + tid; h2[ro + j] = f2bf(loc[it] * r * scale2[j]); }
}

// ---- y = bf16(silu(fc1o + b_fc1)) -------------------------------------
__global__ __launch_bounds__(256) void silu_bias(
    const float* __restrict__ in, const float* __restrict__ bias,
    unsigned short* __restrict__ out) {
  const int idx = blockIdx.x * 256 + threadIdx.x;  // over float4 elems
  const float4 v = ((const float4*)in)[idx];
  const int col = (idx << 2) & (F_ - 1);
  const float z0 = v.x + bias[col], z1 = v.y + bias[col + 1];
  const float z2 = v.z + bias[col + 2], z3 = v.w + bias[col + 3];
  const float s0 = z0 / (1.f + expf(-z0)), s1 = z1 / (1.f + expf(-z1));
  const float s2 = z2 / (1.f + expf(-z2)), s3 = z3 / (1.f + expf(-z3));
  uint2 o;
  o.x = (unsigned)f2bf(s0) | ((unsigned)f2bf(s1) << 16);
  o.y = (unsigned)f2bf(s2) | ((unsigned)f2bf(s3) << 16);
  ((uint2*)out)[idx] = o;
}

// ---- x2 = x1 + gamma2*(fc2o+b2) -> d_out; w3; eta; forget -------------
__global__ __launch_bounds__(256) void add2_norm3(
    const float* __restrict__ x1, const float* __restrict__ fc2o,
    const float* __restrict__ gamma2, const float* __restrict__ bias2,
    const float* __restrict__ scale3, const float* __restrict__ wgate,
    const float* __restrict__ bgate, const float* __restrict__ wforget,
    const float* __restrict__ bforget, float* __restrict__ xout,
    unsigned short* __restrict__ w3, float* __restrict__ eta, float* __restrict__ fg) {
  __shared__ float sbuf[4];
  const int b = blockIdx.x, tid = threadIdx.x;
  const size_t ro = (size_t)b << 10;
  float loc[4]; float ss = 0.f;
#pragma unroll
  for (int it = 0; it < 4; ++it) {
    const int j = (it << 8) + tid;
    const float v = x1[ro + j] + gamma2[j] * (fc2o[ro + j] + bias2[j]);
    xout[ro + j] = v; loc[it] = v; ss += v * v;
  }
  ss = block_sum256(ss, sbuf);
  const float r = rsqrtf(ss * (1.f / 1024.f) + 1e-6f);
  float dg = 0.f, df = 0.f;
#pragma unroll
  for (int it = 0; it < 4; ++it) {
    const int j = (it << 8) + tid;
    const float w = loc[it] * r * scale3[j];
    w3[ro + j] = f2bf(w);
    dg += w * wgate[j]; df += w * wforget[j];
  }
  dg = block_sum256(dg, sbuf);
  df = block_sum256(df, sbuf);
  if (tid == 0) {
    eta[b] = 0.1f / (1.f + expf(-(dg + bgate[0])));
    fg[b] = 0.02f / (1.f + expf(-(df + bforget[0])));
  }
}

// ---- fused value_hat -> err -> memory update --------------------------
// One block per (b, 32-column slab). mem slab staged in LDS: read once,
// write once. 36-float padded stride keeps float4 access at the b128 floor.
__global__ __launch_bounds__(256) void write_update(
    const float* __restrict__ mem, const float* __restrict__ wkey,
    const float* __restrict__ wv_pre, const float* __restrict__ eta,
    const float* __restrict__ fg, const unsigned char* __restrict__ valid,
    float* __restrict__ outm) {
  __shared__ float tile[256][36];
  __shared__ float lwk[256];
  __shared__ float part[8][32];
  __shared__ float lerr[32];
  const int tid = threadIdx.x;
  const int b = blockIdx.x >> 4;
  const int v0 = (blockIdx.x & 15) << 5;  // 32 v per block
  lwk[tid] = wkey[((size_t)b << 8) + tid];
  const int vq = tid & 7, rr = tid >> 3;  // 8 float4 cols x 32 rows/iter
  const float* mb = mem + ((size_t)b << 17) + v0;
#pragma unroll
  for (int it = 0; it < 8; ++it) {
    const int k = (it << 5) + rr;
    *(float4*)&tile[k][vq << 2] = *(const float4*)(mb + ((size_t)k << 9) + (vq << 2));
  }
  __syncthreads();
  {
    const int vv = tid & 31, kg = tid >> 5;
    float p = 0.f;
#pragma unroll 8
    for (int kk = 0; kk < 32; ++kk) { const int k = (kg << 5) + kk; p += tile[k][vv] * lwk[k]; }
    part[kg][vv] = p;
  }
  __syncthreads();
  if (tid < 32) {
    float vh = 0.f;
#pragma unroll
    for (int g = 0; g < 8; ++g) vh += part[g][tid];
    const float wv = tanhf(wv_pre[((size_t)b << 9) + v0 + tid]);
    lerr[tid] = fminf(1.f, fmaxf(-1.f, wv - vh));
  }
  __syncthreads();
  const float et = eta[b], fo = fg[b];
  const float omf = 1.f - fo;
  const bool vb = valid[b] != 0;
  float* ob = outm + ((size_t)b << 17) + v0;
#pragma unroll
  for (int it = 0; it < 8; ++it) {
    const int k = (it << 5) + rr;
    const float wke = lwk[k] * et;
    const float4 m4 = *(const float4*)&tile[k][vq << 2];
    float4 r;
    r.x = omf * m4.x + wke * lerr[(vq << 2) + 0];
    r.y = omf * m4.y + wke * lerr[(vq << 2) + 1];
    r.z = omf * m4.z + wke * lerr[(vq << 2) + 2];
    r.w = omf * m4.w + wke * lerr[(vq << 2) + 3];
    r.x = fminf(10.f, fmaxf(-10.f, r.x));
    r.y = fminf(10.f, fmaxf(-10.f, r.y));
    r.z = fminf(10.f, fmaxf(-10.f, r.z));
    r.w = fminf(10.f, fmaxf(-10.f, r.w));
    if (!vb) { r.x = m4.x; r.y = m4.y; r.z = m4.z; r.w = m4.w; }
    *(float4*)(ob + ((size_t)k << 9) + (vq << 2)) = r;
  }
}

// ---- host -------------------------------------------------------------
extern "C" void kernel_launch(void* const* d_in, const int* in_sizes, int n_in,
                              void* d_out, int out_size, void* d_ws, size_t ws_size,
                              hipStream_t stream) {
  const float* x = (const float*)d_in[0];
  const float* mem = (const float*)d_in[1];
  const unsigned char* valid = (const unsigned char*)d_in[2];
  const float* w_rk = (const float*)d_in[3];
  const float* w_wk = (const float*)d_in[4];
  const float* w_wv = (const float*)d_in[5];
  const float* w_rp = (const float*)d_in[6];
  const float* w_wg = (const float*)d_in[7];
  const float* b_wg = (const float*)d_in[8];
  const float* w_fg = (const float*)d_in[9];
  const float* b_fg = (const float*)d_in[10];
  const float* scale1 = (const float*)d_in[11];
  const float* scale2 = (const float*)d_in[12];
  const float* scale3 = (const float*)d_in[13];
  const float* w_fc1 = (const float*)d_in[14];
  const float* b_fc1 = (const float*)d_in[15];
  const float* w_fc2 = (const float*)d_in[16];
  const float* b_fc2 = (const float*)d_in[17];
  const float* gamma1 = (const float*)d_in[18];
  const float* gamma2 = (const float*)d_in[19];

  char* ws = (char*)d_ws;
  size_t off = 0;
  auto alloc = [&](size_t bytes) -> void* {
    void* p = (void*)(ws + off);
    off = (off + bytes + 255) & ~(size_t)255;
    return p;
  };

  unsigned short* wT_rk = (unsigned short*)alloc((size_t)K_ * H_ * 2);
  unsigned short* wT_wk = (unsigned short*)alloc((size_t)K_ * H_ * 2);
  unsigned short* wT_wv = (unsigned short*)alloc((size_t)V_ * H_ * 2);
  unsigned short* wT_rp = (unsigned short*)alloc((size_t)H_ * V_ * 2);
  unsigned short* wT_f1 = (unsigned short*)alloc((size_t)F_ * H_ * 2);
  unsigned short* wT_f2 = (unsigned short*)alloc((size_t)H_ * F_ * 2);
  unsigned short* h1 = (unsigned short*)alloc((size_t)B_ * H_ * 2);
  float* rk_pre = (float*)alloc((size_t)B_ * K_ * 4);
  float* rkey = (float*)alloc((size_t)B_ * K_ * 4);
  unsigned short* rv = (unsigned short*)alloc((size_t)B_ * V_ * 2);
  float* projo = (float*)alloc((size_t)B_ * H_ * 4);
  float* x1 = (float*)alloc((size_t)B_ * H_ * 4);
  unsigned short* h2 = (unsigned short*)alloc((size_t)B_ * H_ * 2);
  float* fc1o = (float*)alloc((size_t)B_ * F_ * 4);
  unsigned short* ybf = (unsigned short*)alloc((size_t)B_ * F_ * 2);
  float* fc2o = (float*)alloc((size_t)B_ * H_ * 4);
  unsigned short* w3 = (unsigned short*)alloc((size_t)B_ * H_ * 2);
  float* wk_pre = (float*)alloc((size_t)B_ * K_ * 4);
  float* wkey = (float*)alloc((size_t)B_ * K_ * 4);
  float* wv_pre = (float*)alloc((size_t)B_ * V_ * 4);
  float* eta = (float*)alloc((size_t)B_ * 4);
  float* fg = (float*)alloc((size_t)B_ * 4);

  float* xout = (float*)d_out;
  float* outm = (float*)d_out + (size_t)B_ * H_;

  // weight transposes (f32 [R][C] -> bf16 [C][R])
  transpose_bf16<<<dim3(K_ / 32, H_ / 32), 256, 0, stream>>>(w_rk, wT_rk, H_, K_);
  transpose_bf16<<<dim3(K_ / 32, H_ / 32), 256, 0, stream>>>(w_wk, wT_wk, H_, K_);
  transpose_bf16<<<dim3(V_ / 32, H_ / 32), 256, 0, stream>>>(w_wv, wT_wv, H_, V_);
  transpose_bf16<<<dim3(H_ / 32, V_ / 32), 256, 0, stream>>>(w_rp, wT_rp, V_, H_);
  transpose_bf16<<<dim3(F_ / 32, H_ / 32), 256, 0, stream>>>(w_fc1, wT_f1, H_, F_);
  transpose_bf16<<<dim3(H_ / 32, F_ / 32), 256, 0, stream>>>(w_fc2, wT_f2, F_, H_);

  // read path
  norm1_kernel<<<B_, 256, 0, stream>>>(x, scale1, h1);
  gemm_bt<<<dim3(K_ / 64, B_ / 64), 256, 0, stream>>>(h1, wT_rk, rk_pre, B_, K_, H_);
  rmsnorm256<<<B_, 256, 0, stream>>>(rk_pre, rkey, 0.0625f);
  read_einsum<<<B_ * 4, 256, 0, stream>>>(mem, rkey, rv);
  gemm_bt<<<dim3(H_ / 64, B_ / 64), 256, 0, stream>>>(rv, wT_rp, projo, B_, H_, V_);
  add1_norm2<<<B_, 256, 0, stream>>>(x, projo, gamma1, scale2, x1, h2);

  // MLP
  gemm_bt<<<dim3(F_ / 64, B_ / 64), 256, 0, stream>>>(h2, wT_f1, fc1o, B_, F_, H_);
  silu_bias<<<(B_ * F_ / 4) / 256, 256, 0, stream>>>(fc1o, b_fc1, ybf);
  gemm_bt<<<dim3(H_ / 64, B_ / 64), 256, 0, stream>>>(ybf, wT_f2, fc2o, B_, H_, F_);
  add2_norm3<<<B_, 256, 0, stream>>>(x1, fc2o, gamma2, b_fc2, scale3, w_wg, b_wg,
                                     w_fg, b_fg, xout, w3, eta, fg);

  // write path
  gemm_bt<<<dim3(K_ / 64, B_ / 64), 256, 0, stream>>>(w3, wT_wk, wk_pre, B_, K_, H_);
  gemm_bt<<<dim3(V_ / 64, B_ / 64), 256, 0, stream>>>(w3, wT_wv, wv_pre, B_, V_, H_);
  rmsnorm256<<<B_, 256, 0, stream>>>(wk_pre, wkey, 0.0625f);
  write_update<<<B_ * 16, 256, 0, stream>>>(mem, wkey, wv_pre, eta, fg, valid, outm);
}

// Round 2
// 291.722 us; speedup vs baseline: 1.2515x; 1.2515x over previous
//
#include <hip/hip_runtime.h>
#include <math.h>

// PropagatorBlock: B=512, H=1024, K=256, V=512, MUL=4
constexpr int B_ = 512;
constexpr int H_ = 1024;
constexpr int K_ = 256;
constexpr int V_ = 512;
constexpr int F_ = 4096;  // MUL*H

typedef __attribute__((ext_vector_type(8))) short bf16x8;
typedef __attribute__((ext_vector_type(4))) float f32x4;

#define GLD16(gp, lp)                                                   \
  __builtin_amdgcn_global_load_lds(                                     \
      (const __attribute__((address_space(1))) void*)(gp),              \
      (__attribute__((address_space(3))) void*)(lp), 16, 0, 0)

// ---- helpers ----------------------------------------------------------
static __device__ __forceinline__ unsigned short f2bf(float f) {
  union { float f; unsigned int u; } a; a.f = f;
  unsigned int u = a.u;
  return (unsigned short)((u + 0x7FFFu + ((u >> 16) & 1u)) >> 16);  // RNE
}

static __device__ __forceinline__ float block_sum256(float v, float* sbuf) {
#pragma unroll
  for (int o = 32; o > 0; o >>= 1) v += __shfl_down(v, o, 64);
  const int w = threadIdx.x >> 6;
  __syncthreads();
  if ((threadIdx.x & 63) == 0) sbuf[w] = v;
  __syncthreads();
  return sbuf[0] + sbuf[1] + sbuf[2] + sbuf[3];
}

// ---- all 6 weight transposes in one kernel ----------------------------
struct TJob { const float* src; unsigned short* dst; int R, C, cb, blk0; };
struct TArgs { TJob j[6]; };

__global__ __launch_bounds__(256) void transpose_all(TArgs args) {
  __shared__ float t[32][33];
  const int id = blockIdx.x;
  int ji = 0;
#pragma unroll
  for (int i = 1; i < 6; ++i) if (id >= args.j[i].blk0) ji = i;
  const TJob J = args.j[ji];
  const int lb = id - J.blk0;
  const int bx = lb % J.cb, by = lb / J.cb;
  const int tx = threadIdx.x & 31, ty = threadIdx.x >> 5;
  const int c0 = bx << 5, r0 = by << 5;
#pragma unroll
  for (int i = 0; i < 32; i += 8) t[ty + i][tx] = J.src[(size_t)(r0 + ty + i) * J.C + c0 + tx];
  __syncthreads();
#pragma unroll
  for (int i = 0; i < 32; i += 8)
    J.dst[(size_t)(c0 + ty + i) * J.R + r0 + tx] = f2bf(t[tx][ty + i]);
}

// ---- GEMM v2: C[M][N] = A[M][K] * BT[N][K]^T --------------------------
// 64 x BN tile, BK=64, 4 waves (2x2), global_load_lds staging, XOR-swizzled
// chunk layout (pre-swizzled global source; linear LDS dest as gload_lds
// requires). SILU: epilogue z=acc+bias -> silu -> bf16 store.
template <int BN, bool SILU>
__global__ __launch_bounds__(256) void gemm2(
    const unsigned short* __restrict__ A, const unsigned short* __restrict__ BT,
    float* __restrict__ Cf, unsigned short* __restrict__ Cb,
    const float* __restrict__ bias, int M, int N, int K, int Ksub) {
  __shared__ unsigned short lsa[64 * 64];
  __shared__ unsigned short lsb[BN * 64];
  const int tid = threadIdx.x;
  const int m0 = blockIdx.y << 6, n0 = blockIdx.x * BN;
  const int kbeg = blockIdx.z * Ksub;
  const int w = tid >> 6, l = tid & 63;
  const int l15 = l & 15, lg = l >> 4;
  const int wm = (w >> 1) * 32, wn = (w & 1) * (BN / 2);
  constexpr int NF = BN / 32;  // 2 or 4 n-fragments per wave
  f32x4 acc[2][NF] = {};

  const int sr = l >> 3;              // row-in-wave 0..7
  const int sc = ((l & 7) ^ sr) * 8;  // swizzled col chunk (elements)
  const int srow = w * 8 + sr;
  const unsigned short* ga0 = A + (size_t)(m0 + srow) * K + sc;
  const unsigned short* gb0 = BT + (size_t)(n0 + srow) * K + sc;
  const int rx = l15 & 7;  // row&7 on the read side

  for (int k0 = kbeg; k0 < kbeg + Ksub; k0 += 64) {
#pragma unroll
    for (int c = 0; c < 2; ++c)
      GLD16(ga0 + (size_t)(c * 32) * K + k0, &lsa[c * 2048 + w * 512]);
#pragma unroll
    for (int c = 0; c < NF; ++c)
      GLD16(gb0 + (size_t)(c * 32) * K + k0, &lsb[c * 2048 + w * 512]);
    __syncthreads();
    bf16x8 af[2][2], bv[2][NF];
#pragma unroll
    for (int kh = 0; kh < 2; ++kh) {
      const int ch = ((kh * 4 + lg) ^ rx) * 8;
#pragma unroll
      for (int mf = 0; mf < 2; ++mf)
        af[kh][mf] = *(const bf16x8*)&lsa[(wm + mf * 16 + l15) * 64 + ch];
#pragma unroll
      for (int nf = 0; nf < NF; ++nf)
        bv[kh][nf] = *(const bf16x8*)&lsb[(wn + nf * 16 + l15) * 64 + ch];
    }
#pragma unroll
    for (int kh = 0; kh < 2; ++kh)
#pragma unroll
      for (int mf = 0; mf < 2; ++mf)
#pragma unroll
        for (int nf = 0; nf < NF; ++nf)
          acc[mf][nf] = __builtin_amdgcn_mfma_f32_16x16x32_bf16(
              af[kh][mf], bv[kh][nf], acc[mf][nf], 0, 0, 0);
    __syncthreads();
  }

  if constexpr (SILU) {
#pragma unroll
    for (int mf = 0; mf < 2; ++mf)
#pragma unroll
      for (int nf = 0; nf < NF; ++nf) {
        const int col = n0 + wn + nf * 16 + l15;
        const float bi = bias[col];
#pragma unroll
        for (int i = 0; i < 4; ++i) {
          const int row = m0 + wm + mf * 16 + (lg << 2) + i;
          const float z = acc[mf][nf][i] + bi;
          Cb[(size_t)row * N + col] = f2bf(z / (1.f + expf(-z)));
        }
      }
  } else {
    float* Cz = Cf + (size_t)blockIdx.z * M * N;
#pragma unroll
    for (int mf = 0; mf < 2; ++mf)
#pragma unroll
      for (int nf = 0; nf < NF; ++nf) {
        const int r = m0 + wm + mf * 16 + (lg << 2);
        const int c = n0 + wn + nf * 16 + l15;
        float* cp = Cz + (size_t)r * N + c;
#pragma unroll
        for (int i = 0; i < 4; ++i) cp[(size_t)i * N] = acc[mf][nf][i];
      }
  }
}

// ---- norm1: h1 = bf16(rmsnorm(x)*scale1) ------------------------------
__global__ __launch_bounds__(256) void norm1_kernel(
    const float* __restrict__ x, const float* __restrict__ scale,
    unsigned short* __restrict__ out) {
  __shared__ float sbuf[4];
  const int b = blockIdx.x, tid = threadIdx.x;
  const float* xr = x + ((size_t)b << 10);
  float loc[4]; float ss = 0.f;
#pragma unroll
  for (int it = 0; it < 4; ++it) { float v = xr[(it << 8) + tid]; loc[it] = v; ss += v * v; }
  ss = block_sum256(ss, sbuf);
  const float r = rsqrtf(ss * (1.f / 1024.f) + 1e-6f);
  unsigned short* orow = out + ((size_t)b << 10);
#pragma unroll
  for (int it = 0; it < 4; ++it) { const int j = (it << 8) + tid; orow[j] = f2bf(loc[it] * r * scale[j]); }
}

// ---- einsum1 (+fused read_key rmsnorm): rv[b,v] = sum_k mem*rk --------
__global__ __launch_bounds__(256) void read_einsum(
    const float* __restrict__ mem, const float* __restrict__ rk_pre,
    unsigned short* __restrict__ rv) {
  __shared__ float sbuf[4];
  __shared__ float lrk[256];
  __shared__ float part[8][32][4];
  const int tid = threadIdx.x;
  const int b = blockIdx.x >> 2;
  const int v0 = (blockIdx.x & 3) << 7;  // 128 v per block
  {
    const float v = rk_pre[((size_t)b << 8) + tid];
    const float ss = block_sum256(v * v, sbuf);
    lrk[tid] = v * rsqrtf(ss * (1.f / 256.f) + 1e-6f) * 0.0625f;
  }
  __syncthreads();
  const int vq = tid & 31, kg = tid >> 5;
  const float* base = mem + (((size_t)b << 8) + (kg << 5)) * 512 + v0 + (vq << 2);
  float a0 = 0, a1 = 0, a2 = 0, a3 = 0;
#pragma unroll 8
  for (int kk = 0; kk < 32; ++kk) {
    const float4 m4 = *(const float4*)(base + (size_t)kk * 512);
    const float s = lrk[(kg << 5) + kk];
    a0 += s * m4.x; a1 += s * m4.y; a2 += s * m4.z; a3 += s * m4.w;
  }
  part[kg][vq][0] = a0; part[kg][vq][1] = a1; part[kg][vq][2] = a2; part[kg][vq][3] = a3;
  __syncthreads();
  if (kg == 0) {
    float s0 = 0, s1 = 0, s2 = 0, s3 = 0;
#pragma unroll
    for (int g = 0; g < 8; ++g) {
      s0 += part[g][vq][0]; s1 += part[g][vq][1]; s2 += part[g][vq][2]; s3 += part[g][vq][3];
    }
    const size_t o = ((size_t)b << 9) + v0 + (vq << 2);
    rv[o] = f2bf(s0); rv[o + 1] = f2bf(s1); rv[o + 2] = f2bf(s2); rv[o + 3] = f2bf(s3);
  }
}

// ---- x1 = x + gamma1*proj; h2 = bf16(rmsnorm(x1)*scale2) --------------
__global__ __launch_bounds__(256) void add1_norm2(
    const float* __restrict__ x, const float* __restrict__ proj,
    const float* __restrict__ gamma1, const float* __restrict__ scale2,
    float* __restrict__ x1, unsigned short* __restrict__ h2) {
  __shared__ float sbuf[4];
  const int b = blockIdx.x, tid = threadIdx.x;
  const size_t ro = (size_t)b << 10;
  float loc[4]; float ss = 0.f;
#pragma unroll
  for (int it = 0; it < 4; ++it) {
    const int j = (it << 8) + tid;
    const float v = x[ro + j] + gamma1[j] * proj[ro + j];
    x1[ro + j] = v; loc[it] = v; ss += v * v;
  }
  ss = block_sum256(ss, sbuf);
  const float r = rsqrtf(ss * (1.f / 1024.f) + 1e-6f);
#pragma unroll
  for (int it = 0; it < 4; ++it) { const int j = (it << 8) + tid; h2[ro + j] = f2bf(loc[it] * r * scale2[j]); }
}

// ---- x2 = x1 + gamma2*(sum_z fc2p[z]+b2); w3; eta; forget -------------
__global__ __launch_bounds__(256) void add2_norm3(
    const float* __restrict__ x1, const float* __restrict__ fc2p,
    const float* __restrict__ gamma2, const float* __restrict__ bias2,
    const float* __restrict__ scale3, const float* __restrict__ wgate,
    const float* __restrict__ bgate, const float* __restrict__ wforget,
    const float* __restrict__ bforget, float* __restrict__ xout,
    unsigned short* __restrict__ w3, float* __restrict__ eta, float* __restrict__ fg) {
  __shared__ float sbuf[4];
  const int b = blockIdx.x, tid = threadIdx.x;
  const size_t ro = (size_t)b << 10;
  constexpr size_t PS = (size_t)B_ * H_;
  float loc[4]; float ss = 0.f;
#pragma unroll
  for (int it = 0; it < 4; ++it) {
    const int j = (it << 8) + tid;
    float acc = bias2[j];
#pragma unroll
    for (int z = 0; z < 4; ++z) acc += fc2p[z * PS + ro + j];
    const float v = x1[ro + j] + gamma2[j] * acc;
    xout[ro + j] = v; loc[it] = v; ss += v * v;
  }
  ss = block_sum256(ss, sbuf);
  const float r = rsqrtf(ss * (1.f / 1024.f) + 1e-6f);
  float dg = 0.f, df = 0.f;
#pragma unroll
  for (int it = 0; it < 4; ++it) {
    const int j = (it << 8) + tid;
    const float w = loc[it] * r * scale3[j];
    w3[ro + j] = f2bf(w);
    dg += w * wgate[j]; df += w * wforget[j];
  }
  dg = block_sum256(dg, sbuf);
  df = block_sum256(df, sbuf);
  if (tid == 0) {
    eta[b] = 0.1f / (1.f + expf(-(dg + bgate[0])));
    fg[b] = 0.02f / (1.f + expf(-(df + bforget[0])));
  }
}

// ---- fused wkey-rmsnorm -> value_hat -> err -> memory update ----------
__global__ __launch_bounds__(256) void write_update(
    const float* __restrict__ mem, const float* __restrict__ wk_pre,
    const float* __restrict__ wv_pre, const float* __restrict__ eta,
    const float* __restrict__ fg, const unsigned char* __restrict__ valid,
    float* __restrict__ outm) {
  __shared__ float sbuf[4];
  __shared__ float tile[256][36];
  __shared__ float lwk[256];
  __shared__ float part[8][32];
  __shared__ float lerr[32];
  const int tid = threadIdx.x;
  const int b = blockIdx.x >> 4;
  const int v0 = (blockIdx.x & 15) << 5;  // 32 v per block
  {
    const float v = wk_pre[((size_t)b << 8) + tid];
    const float ss = block_sum256(v * v, sbuf);
    lwk[tid] = v * rsqrtf(ss * (1.f / 256.f) + 1e-6f) * 0.0625f;
  }
  const int vq = tid & 7, rr = tid >> 3;
  const float* mb = mem + ((size_t)b << 17) + v0;
#pragma unroll
  for (int it = 0; it < 8; ++it) {
    const int k = (it << 5) + rr;
    *(float4*)&tile[k][vq << 2] = *(const float4*)(mb + ((size_t)k << 9) + (vq << 2));
  }
  __syncthreads();
  {
    const int vv = tid & 31, kg = tid >> 5;
    float p = 0.f;
#pragma unroll 8
    for (int kk = 0; kk < 32; ++kk) { const int k = (kg << 5) + kk; p += tile[k][vv] * lwk[k]; }
    part[kg][vv] = p;
  }
  __syncthreads();
  if (tid < 32) {
    float vh = 0.f;
#pragma unroll
    for (int g = 0; g < 8; ++g) vh += part[g][tid];
    const float wv = tanhf(wv_pre[((size_t)b << 9) + v0 + tid]);
    lerr[tid] = fminf(1.f, fmaxf(-1.f, wv - vh));
  }
  __syncthreads();
  const float et = eta[b], fo = fg[b];
  const float omf = 1.f - fo;
  const bool vb = valid[b] != 0;
  float* ob = outm + ((size_t)b << 17) + v0;
#pragma unroll
  for (int it = 0; it < 8; ++it) {
    const int k = (it << 5) + rr;
    const float wke = lwk[k] * et;
    const float4 m4 = *(const float4*)&tile[k][vq << 2];
    float4 r;
    r.x = omf * m4.x + wke * lerr[(vq << 2) + 0];
    r.y = omf * m4.y + wke * lerr[(vq << 2) + 1];
    r.z = omf * m4.z + wke * lerr[(vq << 2) + 2];
    r.w = omf * m4.w + wke * lerr[(vq << 2) + 3];
    r.x = fminf(10.f, fmaxf(-10.f, r.x));
    r.y = fminf(10.f, fmaxf(-10.f, r.y));
    r.z = fminf(10.f, fmaxf(-10.f, r.z));
    r.w = fminf(10.f, fmaxf(-10.f, r.w));
    if (!vb) { r.x = m4.x; r.y = m4.y; r.z = m4.z; r.w = m4.w; }
    *(float4*)(ob + ((size_t)k << 9) + (vq << 2)) = r;
  }
}

// ---- host -------------------------------------------------------------
extern "C" void kernel_launch(void* const* d_in, const int* in_sizes, int n_in,
                              void* d_out, int out_size, void* d_ws, size_t ws_size,
                              hipStream_t stream) {
  const float* x = (const float*)d_in[0];
  const float* mem = (const float*)d_in[1];
  const unsigned char* valid = (const unsigned char*)d_in[2];
  const float* w_rk = (const float*)d_in[3];
  const float* w_wk = (const float*)d_in[4];
  const float* w_wv = (const float*)d_in[5];
  const float* w_rp = (const float*)d_in[6];
  const float* w_wg = (const float*)d_in[7];
  const float* b_wg = (const float*)d_in[8];
  const float* w_fg = (const float*)d_in[9];
  const float* b_fg = (const float*)d_in[10];
  const float* scale1 = (const float*)d_in[11];
  const float* scale2 = (const float*)d_in[12];
  const float* scale3 = (const float*)d_in[13];
  const float* w_fc1 = (const float*)d_in[14];
  const float* b_fc1 = (const float*)d_in[15];
  const float* w_fc2 = (const float*)d_in[16];
  const float* b_fc2 = (const float*)d_in[17];
  const float* gamma1 = (const float*)d_in[18];
  const float* gamma2 = (const float*)d_in[19];

  char* ws = (char*)d_ws;
  size_t off = 0;
  auto alloc = [&](size_t bytes) -> void* {
    void* p = (void*)(ws + off);
    off = (off + bytes + 255) & ~(size_t)255;
    return p;
  };

  unsigned short* wT_rk = (unsigned short*)alloc((size_t)K_ * H_ * 2);
  unsigned short* wT_wk = (unsigned short*)alloc((size_t)K_ * H_ * 2);
  unsigned short* wT_wv = (unsigned short*)alloc((size_t)V_ * H_ * 2);
  unsigned short* wT_rp = (unsigned short*)alloc((size_t)H_ * V_ * 2);
  unsigned short* wT_f1 = (unsigned short*)alloc((size_t)F_ * H_ * 2);
  unsigned short* wT_f2 = (unsigned short*)alloc((size_t)H_ * F_ * 2);
  unsigned short* h1 = (unsigned short*)alloc((size_t)B_ * H_ * 2);
  float* rk_pre = (float*)alloc((size_t)B_ * K_ * 4);
  unsigned short* rv = (unsigned short*)alloc((size_t)B_ * V_ * 2);
  float* projo = (float*)alloc((size_t)B_ * H_ * 4);
  float* x1 = (float*)alloc((size_t)B_ * H_ * 4);
  unsigned short* h2 = (unsigned short*)alloc((size_t)B_ * H_ * 2);
  unsigned short* ybf = (unsigned short*)alloc((size_t)B_ * F_ * 2);
  float* fc2p = (float*)alloc((size_t)4 * B_ * H_ * 4);
  unsigned short* w3 = (unsigned short*)alloc((size_t)B_ * H_ * 2);
  float* wk_pre = (float*)alloc((size_t)B_ * K_ * 4);
  float* wv_pre = (float*)alloc((size_t)B_ * V_ * 4);
  float* eta = (float*)alloc((size_t)B_ * 4);
  float* fg = (float*)alloc((size_t)B_ * 4);

  float* xout = (float*)d_out;
  float* outm = (float*)d_out + (size_t)B_ * H_;

  // 1. all weight transposes (f32 [R][C] -> bf16 [C][R])
  TArgs ta;
  int blk = 0;
  auto setj = [&](int i, const float* s, unsigned short* d, int R, int C) {
    ta.j[i] = {s, d, R, C, C / 32, blk};
    blk += (R / 32) * (C / 32);
  };
  setj(0, w_rk, wT_rk, H_, K_);
  setj(1, w_wk, wT_wk, H_, K_);
  setj(2, w_wv, wT_wv, H_, V_);
  setj(3, w_rp, wT_rp, V_, H_);
  setj(4, w_fc1, wT_f1, H_, F_);
  setj(5, w_fc2, wT_f2, F_, H_);
  transpose_all<<<blk, 256, 0, stream>>>(ta);

  // read path
  norm1_kernel<<<B_, 256, 0, stream>>>(x, scale1, h1);
  gemm2<64, false><<<dim3(K_ / 64, B_ / 64), 256, 0, stream>>>(
      h1, wT_rk, rk_pre, nullptr, nullptr, B_, K_, H_, H_);
  read_einsum<<<B_ * 4, 256, 0, stream>>>(mem, rk_pre, rv);
  gemm2<128, false><<<dim3(H_ / 128, B_ / 64), 256, 0, stream>>>(
      rv, wT_rp, projo, nullptr, nullptr, B_, H_, V_, V_);
  add1_norm2<<<B_, 256, 0, stream>>>(x, projo, gamma1, scale2, x1, h2);

  // MLP
  gemm2<128, true><<<dim3(F_ / 128, B_ / 64), 256, 0, stream>>>(
      h2, wT_f1, nullptr, ybf, b_fc1, B_, F_, H_, H_);
  gemm2<128, false><<<dim3(H_ / 128, B_ / 64, 4), 256, 0, stream>>>(
      ybf, wT_f2, fc2p, nullptr, nullptr, B_, H_, F_, F_ / 4);
  add2_norm3<<<B_, 256, 0, stream>>>(x1, fc2p, gamma2, b_fc2, scale3, w_wg, b_wg,
                                     w_fg, b_fg, xout, w3, eta, fg);

  // write path
  gemm2<64, false><<<dim3(K_ / 64, B_ / 64), 256, 0, stream>>>(
      w3, wT_wk, wk_pre, nullptr, nullptr, B_, K_, H_, H_);
  gemm2<64, false><<<dim3(V_ / 64, B_ / 64), 256, 0, stream>>>(
      w3, wT_wv, wv_pre, nullptr, nullptr, B_, V_, H_, H_);
  write_update<<<B_ * 16, 256, 0, stream>>>(mem, wk_pre, wv_pre, eta, fg, valid, outm);
}